// Round 1
// baseline (315.447 us; speedup 1.0000x reference)
//
#include <hip/hip_runtime.h>

// ---------- types ----------
typedef unsigned short u16;
typedef __bf16 bf16x8 __attribute__((ext_vector_type(8)));
typedef float f32x4 __attribute__((ext_vector_type(4)));
typedef u16 u16x4 __attribute__((ext_vector_type(4)));
typedef unsigned int uint;

// B=2, T=2048, DM=1024, H=16, DH=64, M = B*T = 4096
#define DM 1024
#define MROWS 4096
#define TSEQ 2048

static __device__ __forceinline__ u16 f2b(float f) {
  uint u = __builtin_bit_cast(uint, f);
  uint r = (u + 0x7fffu + ((u >> 16) & 1u)) >> 16;  // RTN-even
  return (u16)r;
}

// ---------- f32 -> bf16 conversion ----------
__global__ __launch_bounds__(256) void cvt_kernel(const float* __restrict__ in,
                                                  u16* __restrict__ out, int n) {
  int i = (blockIdx.x * 256 + threadIdx.x) * 4;
  if (i >= n) return;
  float4 v = *(const float4*)(in + i);
  u16x4 o;
  o.x = f2b(v.x); o.y = f2b(v.y); o.z = f2b(v.z); o.w = f2b(v.w);
  *(u16x4*)(out + i) = o;
}

// ---------- GEMM core: C[128x128] = A[128xK] * W[128xK]^T, K=1024 ----------
// LDS layout: linear row-major [128][32] bf16 per tile, XOR swizzle on bits 4-5
// with bits 7-8 (applied to stage-source addr and to ds_read addr).
#define SWZ(o) ((o) ^ ((((o) >> 7) & 3) << 4))

static __device__ __forceinline__ void gemm_tile(const u16* __restrict__ A,
                                                 const u16* __restrict__ W,
                                                 int row0, int col0,
                                                 char* ldsA, char* ldsB,
                                                 f32x4 (&acc)[4][4]) {
  const int tid = threadIdx.x;
  const int lane = tid & 63, wid = tid >> 6;
  const int wr = wid >> 1, wc = wid & 1;
  const int lg = lane >> 4, lr = lane & 15;

  f32x4 z = {0.f, 0.f, 0.f, 0.f};
#pragma unroll
  for (int m = 0; m < 4; ++m)
#pragma unroll
    for (int n = 0; n < 4; ++n) acc[m][n] = z;

  for (int k0 = 0; k0 < DM; k0 += 32) {
#pragma unroll
    for (int c = 0; c < 2; ++c) {
      int lin = (c * 256 + tid) * 16;          // linear LDS byte offset
      int p = SWZ(lin);                        // tile byte position to fetch
      int rowl = p >> 6;                       // tile row (64B per row)
      int cb = p & 63;                         // byte within row
      const char* ga = (const char*)(A + (size_t)(row0 + rowl) * DM + k0) + cb;
      __builtin_amdgcn_global_load_lds(
          (const __attribute__((address_space(1))) void*)ga,
          (__attribute__((address_space(3))) void*)(ldsA + lin), 16, 0, 0);
      const char* gb = (const char*)(W + (size_t)(col0 + rowl) * DM + k0) + cb;
      __builtin_amdgcn_global_load_lds(
          (const __attribute__((address_space(1))) void*)gb,
          (__attribute__((address_space(3))) void*)(ldsB + lin), 16, 0, 0);
    }
    __syncthreads();

    bf16x8 av[4], bv[4];
#pragma unroll
    for (int m = 0; m < 4; ++m) {
      int bo = (wr * 64 + m * 16 + lr) * 64 + lg * 16;
      av[m] = *(const bf16x8*)(ldsA + SWZ(bo));
    }
#pragma unroll
    for (int n = 0; n < 4; ++n) {
      int bo = (wc * 64 + n * 16 + lr) * 64 + lg * 16;
      bv[n] = *(const bf16x8*)(ldsB + SWZ(bo));
    }
#pragma unroll
    for (int m = 0; m < 4; ++m)
#pragma unroll
      for (int n = 0; n < 4; ++n)
        acc[m][n] = __builtin_amdgcn_mfma_f32_16x16x32_bf16(av[m], bv[n], acc[m][n], 0, 0, 0);
    __syncthreads();
  }
}

// ---------- fused QKV projection ----------
// grid.x = 24 (seg*8 + ntile), grid.y = 32 (mtile). seg: 0=Q, 1=K, 2=V(->VT)
__global__ __launch_bounds__(256) void qkv_gemm(
    const u16* __restrict__ xb, const u16* __restrict__ Wqb,
    const u16* __restrict__ Wkb, const u16* __restrict__ Wvb,
    const float* __restrict__ bq, const float* __restrict__ bk,
    const float* __restrict__ bv, u16* __restrict__ Qb, u16* __restrict__ Kb,
    u16* __restrict__ VT) {
  __shared__ char lds[16384];
  const int seg = blockIdx.x >> 3, nt = blockIdx.x & 7;
  const int row0 = blockIdx.y * 128, col0 = nt * 128;
  const u16* W = (seg == 0) ? Wqb : (seg == 1) ? Wkb : Wvb;
  const float* bias = (seg == 0) ? bq : (seg == 1) ? bk : bv;

  f32x4 acc[4][4];
  gemm_tile(xb, W, row0, col0, lds, lds + 8192, acc);

  const int tid = threadIdx.x;
  const int lane = tid & 63, wid = tid >> 6;
  const int wr = wid >> 1, wc = wid & 1;
  const int lg = lane >> 4, lr = lane & 15;

  if (seg < 2) {
    u16* out = (seg == 0) ? Qb : Kb;
#pragma unroll
    for (int m = 0; m < 4; ++m)
#pragma unroll
      for (int n = 0; n < 4; ++n) {
        int col = col0 + wc * 64 + n * 16 + lr;
        float b = bias[col];
#pragma unroll
        for (int r = 0; r < 4; ++r) {
          int row = row0 + wr * 64 + m * 16 + lg * 4 + r;
          out[(size_t)row * DM + col] = f2b(acc[m][n][r] + b);
        }
      }
  } else {
    // write transposed: VT[((bi*16+h)*64+dd)*2048 + t], pack 4 t's per store
#pragma unroll
    for (int m = 0; m < 4; ++m)
#pragma unroll
      for (int n = 0; n < 4; ++n) {
        int col = col0 + wc * 64 + n * 16 + lr;
        float b = bias[col];
        int t = row0 + wr * 64 + m * 16 + lg * 4;
        int bi = t >> 11, tt = t & 2047;
        int hh = col >> 6, dd = col & 63;
        u16x4 pk;
        pk.x = f2b(acc[m][n][0] + b);
        pk.y = f2b(acc[m][n][1] + b);
        pk.z = f2b(acc[m][n][2] + b);
        pk.w = f2b(acc[m][n][3] + b);
        *(u16x4*)(VT + ((size_t)((bi * 16 + hh) * 64 + dd)) * 2048 + tt) = pk;
      }
  }
}

// ---------- flash attention (causal) ----------
// grid.x = 32 q-tiles (64 rows each), grid.y = 32 (b*16+h). 4 waves/block,
// each wave owns 16 q-rows. KBLK = 32.
__global__ __launch_bounds__(256) void attn_kernel(const u16* __restrict__ Q,
                                                   const u16* __restrict__ K,
                                                   const u16* __restrict__ VT,
                                                   u16* __restrict__ Aout) {
  __shared__ u16 P_lds[4][512];  // per-wave 16x32 bf16, swizzled
  const int tid = threadIdx.x, lane = tid & 63, wid = tid >> 6;
  const int lg = lane >> 4, lr = lane & 15;
  const int qt = blockIdx.x, bh = blockIdx.y;
  const int b = bh >> 4, h = bh & 15;
  const int q0 = qt * 64 + wid * 16;

  const u16* Qbase = Q + (size_t)b * TSEQ * DM + h * 64;
  const u16* Kbase = K + (size_t)b * TSEQ * DM + h * 64;
  const u16* Vbase = VT + (size_t)bh * 64 * TSEQ;

  bf16x8 qf[2];
#pragma unroll
  for (int kc = 0; kc < 2; ++kc)
    qf[kc] = *(const bf16x8*)(Qbase + (size_t)(q0 + lr) * DM + kc * 32 + lg * 8);

  f32x4 z = {0.f, 0.f, 0.f, 0.f};
  f32x4 O[4] = {z, z, z, z};
  float mrow[4], lrow[4];
#pragma unroll
  for (int r = 0; r < 4; ++r) { mrow[r] = -1e30f; lrow[r] = 0.f; }

  const int nfull = (q0 + 1) >> 5;   // fully-unmasked 32-col tiles
  const int ntot = (q0 + 47) >> 5;   // total tiles touching row range
  char* Pw = (char*)&P_lds[wid][0];

  for (int kt = 0; kt < ntot; ++kt) {
    const int kt0 = kt * 32;
    const bool masked = (kt >= nfull);
    f32x4 s[2] = {z, z};
#pragma unroll
    for (int nc = 0; nc < 2; ++nc) {
      const u16* Kp = Kbase + (size_t)(kt0 + nc * 16 + lr) * DM;
#pragma unroll
      for (int kc = 0; kc < 2; ++kc) {
        bf16x8 kf = *(const bf16x8*)(Kp + kc * 32 + lg * 8);
        s[nc] = __builtin_amdgcn_mfma_f32_16x16x32_bf16(qf[kc], kf, s[nc], 0, 0, 0);
      }
    }
    float pv[2][4];
#pragma unroll
    for (int nc = 0; nc < 2; ++nc)
#pragma unroll
      for (int r = 0; r < 4; ++r) {
        float v = s[nc][r] * 0.125f;  // 1/sqrt(64)
        if (masked) {
          int kcol = kt0 + nc * 16 + lr;
          int qrow = q0 + lg * 4 + r;
          if (kcol > qrow) v = -1e30f;
        }
        pv[nc][r] = v;
      }
#pragma unroll
    for (int r = 0; r < 4; ++r) {
      float mx = fmaxf(pv[0][r], pv[1][r]);
      mx = fmaxf(mx, __shfl_xor(mx, 1));
      mx = fmaxf(mx, __shfl_xor(mx, 2));
      mx = fmaxf(mx, __shfl_xor(mx, 4));
      mx = fmaxf(mx, __shfl_xor(mx, 8));
      float nm = fmaxf(mrow[r], mx);
      float sf = __expf(mrow[r] - nm);
      mrow[r] = nm;
      float p0 = __expf(pv[0][r] - nm);
      float p1 = __expf(pv[1][r] - nm);
      pv[0][r] = p0; pv[1][r] = p1;
      float rs = p0 + p1;
      rs += __shfl_xor(rs, 1);
      rs += __shfl_xor(rs, 2);
      rs += __shfl_xor(rs, 4);
      rs += __shfl_xor(rs, 8);
      lrow[r] = lrow[r] * sf + rs;
#pragma unroll
      for (int dn = 0; dn < 4; ++dn) O[dn][r] *= sf;
    }
    // P (acc layout) -> LDS (A-frag layout), swizzled
#pragma unroll
    for (int nc = 0; nc < 2; ++nc)
#pragma unroll
      for (int r = 0; r < 4; ++r) {
        int bo = (lg * 4 + r) * 64 + (nc * 16 + lr) * 2;
        *(u16*)(Pw + SWZ(bo)) = f2b(pv[nc][r]);
      }
    __threadfence_block();  // wave-local: drain ds_writes before cross-lane read
    int rbo = lr * 64 + lg * 16;
    bf16x8 pa = *(const bf16x8*)(Pw + SWZ(rbo));
    const u16* Vp = Vbase + kt0 + lg * 8;
#pragma unroll
    for (int dn = 0; dn < 4; ++dn) {
      bf16x8 vf = *(const bf16x8*)(Vp + (size_t)(dn * 16 + lr) * TSEQ);
      O[dn] = __builtin_amdgcn_mfma_f32_16x16x32_bf16(pa, vf, O[dn], 0, 0, 0);
    }
    __threadfence_block();  // keep next-iter P writes after this read
  }

  u16* Ap = Aout + (size_t)b * TSEQ * DM + h * 64;
#pragma unroll
  for (int r = 0; r < 4; ++r) {
    float inv = 1.0f / lrow[r];
    int qrow = q0 + lg * 4 + r;
#pragma unroll
    for (int dn = 0; dn < 4; ++dn)
      Ap[(size_t)qrow * DM + dn * 16 + lr] = f2b(O[dn][r] * inv);
  }
}

// ---------- output projection: out = attn @ Wo^T + bo (f32 out) ----------
__global__ __launch_bounds__(256) void out_gemm(const u16* __restrict__ attn,
                                                const u16* __restrict__ Wob,
                                                const float* __restrict__ bo,
                                                float* __restrict__ out) {
  __shared__ char lds[16384];
  const int row0 = blockIdx.y * 128, col0 = blockIdx.x * 128;
  f32x4 acc[4][4];
  gemm_tile(attn, Wob, row0, col0, lds, lds + 8192, acc);

  const int tid = threadIdx.x;
  const int lane = tid & 63, wid = tid >> 6;
  const int wr = wid >> 1, wc = wid & 1;
  const int lg = lane >> 4, lr = lane & 15;
#pragma unroll
  for (int m = 0; m < 4; ++m)
#pragma unroll
    for (int n = 0; n < 4; ++n) {
      int col = col0 + wc * 64 + n * 16 + lr;
      float b = bo[col];
#pragma unroll
      for (int r = 0; r < 4; ++r) {
        int row = row0 + wr * 64 + m * 16 + lg * 4 + r;
        out[(size_t)row * DM + col] = acc[m][n][r] + b;
      }
    }
}

extern "C" void kernel_launch(void* const* d_in, const int* in_sizes, int n_in,
                              void* d_out, int out_size, void* d_ws, size_t ws_size,
                              hipStream_t stream) {
  const float* x = (const float*)d_in[0];
  const float* Wq = (const float*)d_in[1];
  const float* bq = (const float*)d_in[2];
  const float* Wk = (const float*)d_in[3];
  const float* bk = (const float*)d_in[4];
  const float* Wv = (const float*)d_in[5];
  const float* bv = (const float*)d_in[6];
  const float* Wo = (const float*)d_in[7];
  const float* bo = (const float*)d_in[8];

  char* ws = (char*)d_ws;
  const size_t MB = 1024 * 1024;
  u16* xb = (u16*)(ws);             // 8 MB (x bf16; reused as attn out later)
  u16* Wqb = (u16*)(ws + 8 * MB);   // 2 MB
  u16* Wkb = (u16*)(ws + 10 * MB);  // 2 MB
  u16* Wvb = (u16*)(ws + 12 * MB);  // 2 MB
  u16* Wob = (u16*)(ws + 14 * MB);  // 2 MB
  u16* Qb = (u16*)(ws + 16 * MB);   // 8 MB
  u16* Kb = (u16*)(ws + 24 * MB);   // 8 MB
  u16* VT = (u16*)(ws + 32 * MB);   // 8 MB   (total 40 MB)
  u16* attnb = xb;                  // alias: xb dead after qkv_gemm

  cvt_kernel<<<4096, 256, 0, stream>>>(x, xb, MROWS * DM);
  cvt_kernel<<<1024, 256, 0, stream>>>(Wq, Wqb, DM * DM);
  cvt_kernel<<<1024, 256, 0, stream>>>(Wk, Wkb, DM * DM);
  cvt_kernel<<<1024, 256, 0, stream>>>(Wv, Wvb, DM * DM);
  cvt_kernel<<<1024, 256, 0, stream>>>(Wo, Wob, DM * DM);

  qkv_gemm<<<dim3(24, 32), 256, 0, stream>>>(xb, Wqb, Wkb, Wvb, bq, bk, bv, Qb, Kb, VT);
  attn_kernel<<<dim3(32, 32), 256, 0, stream>>>(Qb, Kb, VT, attnb);
  out_gemm<<<dim3(8, 32), 256, 0, stream>>>(attnb, Wob, bo, (float*)d_out);
}

// Round 2
// 191.212 us; speedup vs baseline: 1.6497x; 1.6497x over previous
//
#include <hip/hip_runtime.h>

// ---------- types ----------
typedef unsigned short u16;
typedef __bf16 bf16x8 __attribute__((ext_vector_type(8)));
typedef __bf16 bf16x4 __attribute__((ext_vector_type(4)));
typedef float f32x4 __attribute__((ext_vector_type(4)));
typedef float f32x16 __attribute__((ext_vector_type(16)));
typedef u16 u16x4 __attribute__((ext_vector_type(4)));
typedef unsigned int uint;

// B=2, T=2048, DM=1024, H=16, DH=64, M = B*T = 4096
#define DM 1024
#define MROWS 4096
#define TSEQ 2048

static __device__ __forceinline__ u16 f2b(float f) {
  uint u = __builtin_bit_cast(uint, f);
  uint r = (u + 0x7fffu + ((u >> 16) & 1u)) >> 16;  // RTN-even
  return (u16)r;
}

static __device__ __forceinline__ uint pkbf(float a, float b) {
  union { __bf16 h[2]; uint u; } x;
  x.h[0] = (__bf16)a; x.h[1] = (__bf16)b;
  return x.u;
}

// ---------- f32 -> bf16 conversion (optionally scaled) ----------
__global__ __launch_bounds__(256) void cvt_kernel(const float* __restrict__ in,
                                                  u16* __restrict__ out, int n,
                                                  float scale) {
  int i = (blockIdx.x * 256 + threadIdx.x) * 4;
  if (i >= n) return;
  float4 v = *(const float4*)(in + i);
  u16x4 o;
  o.x = f2b(v.x * scale); o.y = f2b(v.y * scale);
  o.z = f2b(v.z * scale); o.w = f2b(v.w * scale);
  *(u16x4*)(out + i) = o;
}

// ---------- GEMM core: C[128x128] = A[128xK] * W[128xK]^T, K=1024 ----------
#define SWZ(o) ((o) ^ ((((o) >> 7) & 3) << 4))

static __device__ __forceinline__ void gemm_tile(const u16* __restrict__ A,
                                                 const u16* __restrict__ W,
                                                 int row0, int col0,
                                                 char* ldsA, char* ldsB,
                                                 f32x4 (&acc)[4][4]) {
  const int tid = threadIdx.x;
  const int lane = tid & 63, wid = tid >> 6;
  const int wr = wid >> 1, wc = wid & 1;
  const int lg = lane >> 4, lr = lane & 15;

  f32x4 z = {0.f, 0.f, 0.f, 0.f};
#pragma unroll
  for (int m = 0; m < 4; ++m)
#pragma unroll
    for (int n = 0; n < 4; ++n) acc[m][n] = z;

  for (int k0 = 0; k0 < DM; k0 += 32) {
#pragma unroll
    for (int c = 0; c < 2; ++c) {
      int lin = (c * 256 + tid) * 16;
      int p = SWZ(lin);
      int rowl = p >> 6;
      int cb = p & 63;
      const char* ga = (const char*)(A + (size_t)(row0 + rowl) * DM + k0) + cb;
      __builtin_amdgcn_global_load_lds(
          (const __attribute__((address_space(1))) void*)ga,
          (__attribute__((address_space(3))) void*)(ldsA + lin), 16, 0, 0);
      const char* gb = (const char*)(W + (size_t)(col0 + rowl) * DM + k0) + cb;
      __builtin_amdgcn_global_load_lds(
          (const __attribute__((address_space(1))) void*)gb,
          (__attribute__((address_space(3))) void*)(ldsB + lin), 16, 0, 0);
    }
    __syncthreads();

    bf16x8 av[4], bv[4];
#pragma unroll
    for (int m = 0; m < 4; ++m) {
      int bo = (wr * 64 + m * 16 + lr) * 64 + lg * 16;
      av[m] = *(const bf16x8*)(ldsA + SWZ(bo));
    }
#pragma unroll
    for (int n = 0; n < 4; ++n) {
      int bo = (wc * 64 + n * 16 + lr) * 64 + lg * 16;
      bv[n] = *(const bf16x8*)(ldsB + SWZ(bo));
    }
#pragma unroll
    for (int m = 0; m < 4; ++m)
#pragma unroll
      for (int n = 0; n < 4; ++n)
        acc[m][n] = __builtin_amdgcn_mfma_f32_16x16x32_bf16(av[m], bv[n], acc[m][n], 0, 0, 0);
    __syncthreads();
  }
}

// ---------- fused QKV projection ----------
__global__ __launch_bounds__(256) void qkv_gemm(
    const u16* __restrict__ xb, const u16* __restrict__ Wqb,
    const u16* __restrict__ Wkb, const u16* __restrict__ Wvb,
    const float* __restrict__ bq, const float* __restrict__ bk,
    const float* __restrict__ bv, u16* __restrict__ Qb, u16* __restrict__ Kb,
    u16* __restrict__ VT) {
  __shared__ char lds[16384];
  const int seg = blockIdx.x >> 3, nt = blockIdx.x & 7;
  const int row0 = blockIdx.y * 128, col0 = nt * 128;
  const u16* W = (seg == 0) ? Wqb : (seg == 1) ? Wkb : Wvb;
  const float* bias = (seg == 0) ? bq : (seg == 1) ? bk : bv;
  const float bscale = (seg == 0) ? 0.125f : 1.0f;  // 1/sqrt(64) folded into Q

  f32x4 acc[4][4];
  gemm_tile(xb, W, row0, col0, lds, lds + 8192, acc);

  const int tid = threadIdx.x;
  const int lane = tid & 63, wid = tid >> 6;
  const int wr = wid >> 1, wc = wid & 1;
  const int lg = lane >> 4, lr = lane & 15;

  if (seg < 2) {
    u16* out = (seg == 0) ? Qb : Kb;
#pragma unroll
    for (int m = 0; m < 4; ++m)
#pragma unroll
      for (int n = 0; n < 4; ++n) {
        int col = col0 + wc * 64 + n * 16 + lr;
        float b = bias[col] * bscale;
#pragma unroll
        for (int r = 0; r < 4; ++r) {
          int row = row0 + wr * 64 + m * 16 + lg * 4 + r;
          out[(size_t)row * DM + col] = f2b(acc[m][n][r] + b);
        }
      }
  } else {
#pragma unroll
    for (int m = 0; m < 4; ++m)
#pragma unroll
      for (int n = 0; n < 4; ++n) {
        int col = col0 + wc * 64 + n * 16 + lr;
        float b = bias[col];
        int t = row0 + wr * 64 + m * 16 + lg * 4;
        int bi = t >> 11, tt = t & 2047;
        int hh = col >> 6, dd = col & 63;
        u16x4 pk;
        pk.x = f2b(acc[m][n][0] + b);
        pk.y = f2b(acc[m][n][1] + b);
        pk.z = f2b(acc[m][n][2] + b);
        pk.w = f2b(acc[m][n][3] + b);
        *(u16x4*)(VT + ((size_t)((bi * 16 + hh) * 64 + dd)) * 2048 + tt) = pk;
      }
  }
}

// ---------- flash attention (causal), swapped-operand 32x32 structure ------
// Block = 4 waves. Waves 0,1 -> q-tile (31-pr), waves 2,3 -> q-tile pr
// (64 rows each, split in two 32-row wave tiles) => every block does the
// same total kv work (causal balance). No barriers.
// Per wave: S^T = mfma(K,Q) so lane ln&31 owns q-row q0+ln (kv in regs);
// O^T = mfma(V^T, P^T) keeps q on lanes -> per-lane softmax state.
__global__ __launch_bounds__(256) void attn_kernel(const u16* __restrict__ Q,
                                                   const u16* __restrict__ K,
                                                   const u16* __restrict__ VT,
                                                   u16* __restrict__ Aout) {
  __shared__ u16 tb[4][2048];  // per-wave 32x64 transpose buffer (epilogue)
  const int tid = threadIdx.x, lane = tid & 63, wid = tid >> 6;
  const int hi = lane >> 5, ln = lane & 31;
  const int pr = blockIdx.x, bh = blockIdx.y;
  const int b = bh >> 4, h = bh & 15;
  const int qt = (wid < 2) ? (31 - pr) : pr;
  const int q0 = qt * 64 + (wid & 1) * 32;

  const u16* Qb = Q + (size_t)b * TSEQ * DM + h * 64;
  const u16* Kb = K + (size_t)b * TSEQ * DM + h * 64;
  const u16* Vb = VT + (size_t)bh * 64 * TSEQ;

  // Q fragment (B operand): B[n=q=ln][k-slot dh = c*16 + hi*8 + j]
  bf16x8 qf[4];
#pragma unroll
  for (int c = 0; c < 4; ++c)
    qf[c] = *(const bf16x8*)(Qb + (size_t)(q0 + ln) * DM + c * 16 + hi * 8);

  f32x16 Oa, Ob;  // O^T accumulators: d-halves 0..31 / 32..63
#pragma unroll
  for (int r = 0; r < 16; ++r) { Oa[r] = 0.f; Ob[r] = 0.f; }
  float m = -1e30f, l = 0.f;

  const int ntile = (q0 >> 5) + 1;
  for (int kt = 0; kt < ntile; ++kt) {
    const int k0 = kt * 32;
    f32x16 S;
#pragma unroll
    for (int r = 0; r < 16; ++r) S[r] = 0.f;
#pragma unroll
    for (int c = 0; c < 4; ++c) {
      bf16x8 kf = *(const bf16x8*)(Kb + (size_t)(k0 + ln) * DM + c * 16 + hi * 8);
      S = __builtin_amdgcn_mfma_f32_32x32x16_bf16(kf, qf[c], S, 0, 0, 0);
    }
    // S[r] = score(kv = k0 + (r&3)+8*(r>>2)+4*hi, q = q0+ln)
    if (kt == ntile - 1) {  // diagonal tile: mask kv > q
      const int q = q0 + ln;
#pragma unroll
      for (int r = 0; r < 16; ++r) {
        int kv = k0 + (r & 3) + 8 * (r >> 2) + 4 * hi;
        if (kv > q) S[r] = -1e30f;
      }
    }
    // row max: in-lane tree + cross (lane^32 holds other 16 kv of same row)
    float m0 = fmaxf(S[0], S[1]), m1 = fmaxf(S[2], S[3]);
    float m2 = fmaxf(S[4], S[5]), m3 = fmaxf(S[6], S[7]);
    float m4 = fmaxf(S[8], S[9]), m5 = fmaxf(S[10], S[11]);
    float m6 = fmaxf(S[12], S[13]), m7 = fmaxf(S[14], S[15]);
    m0 = fmaxf(m0, m1); m2 = fmaxf(m2, m3);
    m4 = fmaxf(m4, m5); m6 = fmaxf(m6, m7);
    m0 = fmaxf(m0, m2); m4 = fmaxf(m4, m6);
    float mx = fmaxf(m0, m4);
    mx = fmaxf(mx, __shfl_xor(mx, 32));
    // defer-max (T13): only rescale when max grew by > 8
    if (!__all(mx - m <= 8.f)) {
      float nm = fmaxf(m, mx);
      float sf = __expf(m - nm);
      m = nm; l *= sf;
#pragma unroll
      for (int r = 0; r < 16; ++r) { Oa[r] *= sf; Ob[r] *= sf; }
    }
    float p[16];
#pragma unroll
    for (int r = 0; r < 16; ++r) p[r] = __expf(S[r] - m);
    float s0 = p[0] + p[1], s1 = p[2] + p[3], s2 = p[4] + p[5], s3 = p[6] + p[7];
    float s4 = p[8] + p[9], s5 = p[10] + p[11], s6 = p[12] + p[13], s7 = p[14] + p[15];
    s0 += s1; s2 += s3; s4 += s5; s6 += s7;
    s0 += s2; s4 += s6;
    float ts = s0 + s4;
    ts += __shfl_xor(ts, 32);
    l += ts;
    // P^T B-fragment: B[n=q=ln][slot(hi,j)] = p[c*8+j] (kv order permuted;
    // V A-fragment below uses the SAME permuted kv order -> product exact)
    uint pw[8];
#pragma unroll
    for (int i = 0; i < 8; ++i) pw[i] = pkbf(p[2 * i], p[2 * i + 1]);
#pragma unroll
    for (int c = 0; c < 2; ++c) {
      union { uint w[4]; bf16x8 v; } pf;
      pf.w[0] = pw[4 * c + 0]; pf.w[1] = pw[4 * c + 1];
      pf.w[2] = pw[4 * c + 2]; pf.w[3] = pw[4 * c + 3];
      // V^T A-fragment, permuted kv: slots j0..3 at kv0 = k0+c*16+4*hi,
      // slots j4..7 at kv0+8 (two 8B loads from VT[d][t])
#pragma unroll
      for (int hh = 0; hh < 2; ++hh) {
        const u16* vp = Vb + (size_t)(hh * 32 + ln) * TSEQ + k0 + c * 16 + hi * 4;
        union { bf16x4 q[2]; bf16x8 v; } vf;
        vf.q[0] = *(const bf16x4*)vp;
        vf.q[1] = *(const bf16x4*)(vp + 8);
        if (hh == 0)
          Oa = __builtin_amdgcn_mfma_f32_32x32x16_bf16(vf.v, pf.v, Oa, 0, 0, 0);
        else
          Ob = __builtin_amdgcn_mfma_f32_32x32x16_bf16(vf.v, pf.v, Ob, 0, 0, 0);
      }
    }
  }

  // epilogue: normalize, transpose O^T via per-wave LDS, coalesced store
  const float inv = 1.f / l;
  u16* T = &tb[wid][0];
  char* Tc = (char*)T;
#pragma unroll
  for (int i = 0; i < 8; ++i) {
    int d0 = (2 * i & 3) + 8 * ((2 * i) >> 2) + 4 * hi;  // even, pair (d0,d0+1)
    uint wA = pkbf(Oa[2 * i] * inv, Oa[2 * i + 1] * inv);
    *(uint*)(Tc + (ln * 128 + ((d0 * 2) ^ ((ln & 7) << 4)))) = wA;
    uint wB = pkbf(Ob[2 * i] * inv, Ob[2 * i + 1] * inv);
    *(uint*)(Tc + (ln * 128 + (((d0 + 32) * 2) ^ ((ln & 7) << 4)))) = wB;
  }
  __threadfence_block();
  u16* Ap = Aout + (size_t)b * TSEQ * DM + h * 64 + (size_t)(q0 + ln) * DM;
#pragma unroll
  for (int j = 0; j < 4; ++j) {
    int oct = hi * 4 + j;
    bf16x8 v = *(const bf16x8*)(Tc + (ln * 128 + ((oct * 16) ^ ((ln & 7) << 4))));
    *(bf16x8*)(Ap + oct * 8) = v;
  }
}

// ---------- output projection: out = attn @ Wo^T + bo (f32 out) ----------
__global__ __launch_bounds__(256) void out_gemm(const u16* __restrict__ attn,
                                                const u16* __restrict__ Wob,
                                                const float* __restrict__ bo,
                                                float* __restrict__ out) {
  __shared__ char lds[16384];
  const int row0 = blockIdx.y * 128, col0 = blockIdx.x * 128;
  f32x4 acc[4][4];
  gemm_tile(attn, Wob, row0, col0, lds, lds + 8192, acc);

  const int tid = threadIdx.x;
  const int lane = tid & 63, wid = tid >> 6;
  const int wr = wid >> 1, wc = wid & 1;
  const int lg = lane >> 4, lr = lane & 15;
#pragma unroll
  for (int m = 0; m < 4; ++m)
#pragma unroll
    for (int n = 0; n < 4; ++n) {
      int col = col0 + wc * 64 + n * 16 + lr;
      float b = bo[col];
#pragma unroll
      for (int r = 0; r < 4; ++r) {
        int row = row0 + wr * 64 + m * 16 + lg * 4 + r;
        out[(size_t)row * DM + col] = acc[m][n][r] + b;
      }
    }
}

extern "C" void kernel_launch(void* const* d_in, const int* in_sizes, int n_in,
                              void* d_out, int out_size, void* d_ws, size_t ws_size,
                              hipStream_t stream) {
  const float* x = (const float*)d_in[0];
  const float* Wq = (const float*)d_in[1];
  const float* bq = (const float*)d_in[2];
  const float* Wk = (const float*)d_in[3];
  const float* bk = (const float*)d_in[4];
  const float* Wv = (const float*)d_in[5];
  const float* bv = (const float*)d_in[6];
  const float* Wo = (const float*)d_in[7];
  const float* bo = (const float*)d_in[8];

  char* ws = (char*)d_ws;
  const size_t MB = 1024 * 1024;
  u16* xb = (u16*)(ws);             // 8 MB (x bf16; reused as attn out later)
  u16* Wqb = (u16*)(ws + 8 * MB);   // 2 MB
  u16* Wkb = (u16*)(ws + 10 * MB);  // 2 MB
  u16* Wvb = (u16*)(ws + 12 * MB);  // 2 MB
  u16* Wob = (u16*)(ws + 14 * MB);  // 2 MB
  u16* Qb = (u16*)(ws + 16 * MB);   // 8 MB
  u16* Kb = (u16*)(ws + 24 * MB);   // 8 MB
  u16* VT = (u16*)(ws + 32 * MB);   // 8 MB   (total 40 MB)
  u16* attnb = xb;                  // alias: xb dead after qkv_gemm

  cvt_kernel<<<4096, 256, 0, stream>>>(x, xb, MROWS * DM, 1.0f);
  cvt_kernel<<<1024, 256, 0, stream>>>(Wq, Wqb, DM * DM, 0.125f);  // fold 1/sqrt(Dh)
  cvt_kernel<<<1024, 256, 0, stream>>>(Wk, Wkb, DM * DM, 1.0f);
  cvt_kernel<<<1024, 256, 0, stream>>>(Wv, Wvb, DM * DM, 1.0f);
  cvt_kernel<<<1024, 256, 0, stream>>>(Wo, Wob, DM * DM, 1.0f);

  qkv_gemm<<<dim3(24, 32), 256, 0, stream>>>(xb, Wqb, Wkb, Wvb, bq, bk, bv, Qb, Kb, VT);
  attn_kernel<<<dim3(16, 32), 256, 0, stream>>>(Qb, Kb, VT, attnb);
  out_gemm<<<dim3(8, 32), 256, 0, stream>>>(attnb, Wob, bo, (float*)d_out);
}

// Round 3
// 152.892 us; speedup vs baseline: 2.0632x; 1.2506x over previous
//
#include <hip/hip_runtime.h>

// ---------- types ----------
typedef unsigned short u16;
typedef __bf16 bf16x8 __attribute__((ext_vector_type(8)));
typedef float f32x4 __attribute__((ext_vector_type(4)));
typedef float f32x16 __attribute__((ext_vector_type(16)));
typedef u16 u16x4 __attribute__((ext_vector_type(4)));
typedef unsigned int uint;

// B=2, T=2048, DM=1024, H=16, DH=64, M = B*T = 4096
#define DM 1024
#define MROWS 4096
#define TSEQ 2048

static __device__ __forceinline__ u16 f2b(float f) {
  uint u = __builtin_bit_cast(uint, f);
  uint r = (u + 0x7fffu + ((u >> 16) & 1u)) >> 16;  // RTN-even
  return (u16)r;
}

static __device__ __forceinline__ uint pkbf(float a, float b) {
  union { __bf16 h[2]; uint u; } x;
  x.h[0] = (__bf16)a; x.h[1] = (__bf16)b;
  return x.u;
}

// ---------- f32 -> bf16 conversion (optionally scaled) ----------
__global__ __launch_bounds__(256) void cvt_kernel(const float* __restrict__ in,
                                                  u16* __restrict__ out, int n,
                                                  float scale) {
  int i = (blockIdx.x * 256 + threadIdx.x) * 4;
  if (i >= n) return;
  float4 v = *(const float4*)(in + i);
  u16x4 o;
  o.x = f2b(v.x * scale); o.y = f2b(v.y * scale);
  o.z = f2b(v.z * scale); o.w = f2b(v.w * scale);
  *(u16x4*)(out + i) = o;
}

// ---------- GEMM core: C[128x128] = A[128xK] * W[128xK]^T, K=1024 ----------
#define SWZ(o) ((o) ^ ((((o) >> 7) & 3) << 4))

static __device__ __forceinline__ void gemm_tile(const u16* __restrict__ A,
                                                 const u16* __restrict__ W,
                                                 int row0, int col0,
                                                 char* ldsA, char* ldsB,
                                                 f32x4 (&acc)[4][4]) {
  const int tid = threadIdx.x;
  const int lane = tid & 63, wid = tid >> 6;
  const int wr = wid >> 1, wc = wid & 1;
  const int lg = lane >> 4, lr = lane & 15;

  f32x4 z = {0.f, 0.f, 0.f, 0.f};
#pragma unroll
  for (int m = 0; m < 4; ++m)
#pragma unroll
    for (int n = 0; n < 4; ++n) acc[m][n] = z;

  for (int k0 = 0; k0 < DM; k0 += 32) {
#pragma unroll
    for (int c = 0; c < 2; ++c) {
      int lin = (c * 256 + tid) * 16;
      int p = SWZ(lin);
      int rowl = p >> 6;
      int cb = p & 63;
      const char* ga = (const char*)(A + (size_t)(row0 + rowl) * DM + k0) + cb;
      __builtin_amdgcn_global_load_lds(
          (const __attribute__((address_space(1))) void*)ga,
          (__attribute__((address_space(3))) void*)(ldsA + lin), 16, 0, 0);
      const char* gb = (const char*)(W + (size_t)(col0 + rowl) * DM + k0) + cb;
      __builtin_amdgcn_global_load_lds(
          (const __attribute__((address_space(1))) void*)gb,
          (__attribute__((address_space(3))) void*)(ldsB + lin), 16, 0, 0);
    }
    __syncthreads();

    bf16x8 av[4], bv[4];
#pragma unroll
    for (int m = 0; m < 4; ++m) {
      int bo = (wr * 64 + m * 16 + lr) * 64 + lg * 16;
      av[m] = *(const bf16x8*)(ldsA + SWZ(bo));
    }
#pragma unroll
    for (int n = 0; n < 4; ++n) {
      int bo = (wc * 64 + n * 16 + lr) * 64 + lg * 16;
      bv[n] = *(const bf16x8*)(ldsB + SWZ(bo));
    }
#pragma unroll
    for (int m = 0; m < 4; ++m)
#pragma unroll
      for (int n = 0; n < 4; ++n)
        acc[m][n] = __builtin_amdgcn_mfma_f32_16x16x32_bf16(av[m], bv[n], acc[m][n], 0, 0, 0);
    __syncthreads();
  }
}

// ---------- fused QKV projection ----------
__global__ __launch_bounds__(256) void qkv_gemm(
    const u16* __restrict__ xb, const u16* __restrict__ Wqb,
    const u16* __restrict__ Wkb, const u16* __restrict__ Wvb,
    const float* __restrict__ bq, const float* __restrict__ bk,
    const float* __restrict__ bv, u16* __restrict__ Qb, u16* __restrict__ Kb,
    u16* __restrict__ VT) {
  __shared__ char lds[16384];
  const int seg = blockIdx.x >> 3, nt = blockIdx.x & 7;
  const int row0 = blockIdx.y * 128, col0 = nt * 128;
  const u16* W = (seg == 0) ? Wqb : (seg == 1) ? Wkb : Wvb;
  const float* bias = (seg == 0) ? bq : (seg == 1) ? bk : bv;
  // Q carries 1/sqrt(64) * log2(e) so attention works in exp2 domain
  const float bscale = (seg == 0) ? 0.18033688011112042f : 1.0f;

  f32x4 acc[4][4];
  gemm_tile(xb, W, row0, col0, lds, lds + 8192, acc);

  const int tid = threadIdx.x;
  const int lane = tid & 63, wid = tid >> 6;
  const int wr = wid >> 1, wc = wid & 1;
  const int lg = lane >> 4, lr = lane & 15;

  if (seg < 2) {
    u16* out = (seg == 0) ? Qb : Kb;
#pragma unroll
    for (int m = 0; m < 4; ++m)
#pragma unroll
      for (int n = 0; n < 4; ++n) {
        int col = col0 + wc * 64 + n * 16 + lr;
        float b = bias[col] * bscale;
#pragma unroll
        for (int r = 0; r < 4; ++r) {
          int row = row0 + wr * 64 + m * 16 + lg * 4 + r;
          out[(size_t)row * DM + col] = f2b(acc[m][n][r] + b);
        }
      }
  } else {
    // write transposed + kv-bit-swap (bits 2<->3 of t) so attn's PV
    // A-fragment (permuted kv order) is one contiguous b128 load.
#pragma unroll
    for (int m = 0; m < 4; ++m)
#pragma unroll
      for (int n = 0; n < 4; ++n) {
        int col = col0 + wc * 64 + n * 16 + lr;
        float b = bias[col];
        int t = row0 + wr * 64 + m * 16 + lg * 4;
        int bi = t >> 11, tt = t & 2047;
        int tt2 = (tt & ~12) | ((tt & 4) << 1) | ((tt & 8) >> 1);
        int hh = col >> 6, dd = col & 63;
        u16x4 pk;
        pk.x = f2b(acc[m][n][0] + b);
        pk.y = f2b(acc[m][n][1] + b);
        pk.z = f2b(acc[m][n][2] + b);
        pk.w = f2b(acc[m][n][3] + b);
        *(u16x4*)(VT + ((size_t)((bi * 16 + hh) * 64 + dd)) * 2048 + tt2) = pk;
      }
  }
}

// ---------- flash attention (causal), swapped-operand 32x32 structure ------
// Block = 4 waves. Waves 0,1 -> q-tile (31-pr), waves 2,3 -> q-tile pr.
// XCD-aware remap: 4 heads per XCD -> K/V working set 2MB fits 4MB L2.
// Per wave: S^T = mfma(K,Q), lane owns q-row; O^T = mfma(V^T,P^T).
// K/V register-prefetched one tile ahead (ping-pong, unroll 2).
__global__ __launch_bounds__(256, 2) void attn_kernel(const u16* __restrict__ Q,
                                                      const u16* __restrict__ K,
                                                      const u16* __restrict__ VT,
                                                      u16* __restrict__ Aout) {
  __shared__ u16 tb[4][2048];  // per-wave 32x64 transpose buffer (epilogue)
  const int tid = threadIdx.x, lane = tid & 63, wid = tid >> 6;
  const int hi = lane >> 5, ln = lane & 31;
  // XCD swizzle: id&7 = xcd; give each XCD 4 heads x 16 pair-blocks
  const int id = blockIdx.x + (blockIdx.y << 4);
  const int xcd = id & 7, idx = id >> 3;
  const int bh = xcd * 4 + (idx & 3);
  const int pr = idx >> 2;
  const int b = bh >> 4, h = bh & 15;
  const int qt = (wid < 2) ? (31 - pr) : pr;
  const int q0 = qt * 64 + (wid & 1) * 32;

  const u16* Qb = Q + (size_t)b * TSEQ * DM + h * 64;
  const u16* Kb = K + (size_t)b * TSEQ * DM + h * 64;
  const u16* Vb = VT + (size_t)bh * 64 * TSEQ;

  bf16x8 qf[4];
#pragma unroll
  for (int c = 0; c < 4; ++c)
    qf[c] = *(const bf16x8*)(Qb + (size_t)(q0 + ln) * DM + c * 16 + hi * 8);

  f32x16 Oa, Ob;
#pragma unroll
  for (int r = 0; r < 16; ++r) { Oa[r] = 0.f; Ob[r] = 0.f; }
  float m = -1e30f, l = 0.f;

  auto loadK = [&](int k0, bf16x8 (&kf)[4]) {
#pragma unroll
    for (int c = 0; c < 4; ++c)
      kf[c] = *(const bf16x8*)(Kb + (size_t)(k0 + ln) * DM + c * 16 + hi * 8);
  };
  auto loadV = [&](int k0, bf16x8 (&vf)[4]) {
#pragma unroll
    for (int c = 0; c < 2; ++c)
#pragma unroll
      for (int hh = 0; hh < 2; ++hh)
        vf[2 * c + hh] = *(const bf16x8*)(Vb + (size_t)(hh * 32 + ln) * TSEQ +
                                          k0 + c * 16 + hi * 8);
  };
  auto tile = [&](const bf16x8 (&kf)[4], const bf16x8 (&vf)[4], int k0, bool diag) {
    f32x16 S;
#pragma unroll
    for (int r = 0; r < 16; ++r) S[r] = 0.f;
#pragma unroll
    for (int c = 0; c < 4; ++c)
      S = __builtin_amdgcn_mfma_f32_32x32x16_bf16(kf[c], qf[c], S, 0, 0, 0);
    if (diag) {
      const int q = q0 + ln;
#pragma unroll
      for (int r = 0; r < 16; ++r) {
        int kv = k0 + (r & 3) + 8 * (r >> 2) + 4 * hi;
        if (kv > q) S[r] = -1e30f;
      }
    }
    float m0 = fmaxf(fmaxf(S[0], S[1]), fmaxf(S[2], S[3]));
    float m1 = fmaxf(fmaxf(S[4], S[5]), fmaxf(S[6], S[7]));
    float m2 = fmaxf(fmaxf(S[8], S[9]), fmaxf(S[10], S[11]));
    float m3 = fmaxf(fmaxf(S[12], S[13]), fmaxf(S[14], S[15]));
    float mx = fmaxf(fmaxf(m0, m1), fmaxf(m2, m3));
    mx = fmaxf(mx, __shfl_xor(mx, 32));
    if (!__all(mx - m <= 8.f)) {  // defer-max (T13), exp2 domain
      float nm = fmaxf(m, mx);
      float sf = __builtin_amdgcn_exp2f(m - nm);
      m = nm; l *= sf;
#pragma unroll
      for (int r = 0; r < 16; ++r) { Oa[r] *= sf; Ob[r] *= sf; }
    }
    float p[16];
#pragma unroll
    for (int r = 0; r < 16; ++r) p[r] = __builtin_amdgcn_exp2f(S[r] - m);
    float ts = ((p[0] + p[1]) + (p[2] + p[3])) + ((p[4] + p[5]) + (p[6] + p[7]));
    ts += ((p[8] + p[9]) + (p[10] + p[11])) + ((p[12] + p[13]) + (p[14] + p[15]));
    ts += __shfl_xor(ts, 32);
    l += ts;
    uint pw[8];
#pragma unroll
    for (int i = 0; i < 8; ++i) pw[i] = pkbf(p[2 * i], p[2 * i + 1]);
#pragma unroll
    for (int c = 0; c < 2; ++c) {
      union { uint w[4]; bf16x8 v; } pf;
      pf.w[0] = pw[4 * c + 0]; pf.w[1] = pw[4 * c + 1];
      pf.w[2] = pw[4 * c + 2]; pf.w[3] = pw[4 * c + 3];
      Oa = __builtin_amdgcn_mfma_f32_32x32x16_bf16(vf[2 * c + 0], pf.v, Oa, 0, 0, 0);
      Ob = __builtin_amdgcn_mfma_f32_32x32x16_bf16(vf[2 * c + 1], pf.v, Ob, 0, 0, 0);
    }
  };

  const int ntile = (q0 >> 5) + 1;
  bf16x8 kA[4], vA[4], kB[4], vB[4];
  loadK(0, kA); loadV(0, vA);
  int kt = 0;
  for (; kt + 2 <= ntile; kt += 2) {
    loadK((kt + 1) * 32, kB); loadV((kt + 1) * 32, vB);
    tile(kA, vA, kt * 32, false);
    if (kt + 2 < ntile) { loadK((kt + 2) * 32, kA); loadV((kt + 2) * 32, vA); }
    tile(kB, vB, (kt + 1) * 32, kt + 2 == ntile);
  }
  if (kt < ntile) tile(kA, vA, kt * 32, true);

  // epilogue: normalize, transpose O^T via per-wave LDS, coalesced store
  const float inv = 1.f / l;
  char* Tc = (char*)&tb[wid][0];
#pragma unroll
  for (int i = 0; i < 8; ++i) {
    int d0 = (2 * i & 3) + 8 * ((2 * i) >> 2) + 4 * hi;
    uint wA = pkbf(Oa[2 * i] * inv, Oa[2 * i + 1] * inv);
    *(uint*)(Tc + (ln * 128 + ((d0 * 2) ^ ((ln & 7) << 4)))) = wA;
    uint wB = pkbf(Ob[2 * i] * inv, Ob[2 * i + 1] * inv);
    *(uint*)(Tc + (ln * 128 + (((d0 + 32) * 2) ^ ((ln & 7) << 4)))) = wB;
  }
  __threadfence_block();
  u16* Ap = Aout + (size_t)b * TSEQ * DM + h * 64 + (size_t)(q0 + ln) * DM;
#pragma unroll
  for (int j = 0; j < 4; ++j) {
    int oct = hi * 4 + j;
    bf16x8 v = *(const bf16x8*)(Tc + (ln * 128 + ((oct * 16) ^ ((ln & 7) << 4))));
    *(bf16x8*)(Ap + oct * 8) = v;
  }
}

// ---------- output projection: out = attn @ Wo^T + bo (f32 out) ----------
__global__ __launch_bounds__(256) void out_gemm(const u16* __restrict__ attn,
                                                const u16* __restrict__ Wob,
                                                const float* __restrict__ bo,
                                                float* __restrict__ out) {
  __shared__ char lds[16384];
  const int row0 = blockIdx.y * 128, col0 = blockIdx.x * 128;
  f32x4 acc[4][4];
  gemm_tile(attn, Wob, row0, col0, lds, lds + 8192, acc);

  const int tid = threadIdx.x;
  const int lane = tid & 63, wid = tid >> 6;
  const int wr = wid >> 1, wc = wid & 1;
  const int lg = lane >> 4, lr = lane & 15;
#pragma unroll
  for (int m = 0; m < 4; ++m)
#pragma unroll
    for (int n = 0; n < 4; ++n) {
      int col = col0 + wc * 64 + n * 16 + lr;
      float b = bo[col];
#pragma unroll
      for (int r = 0; r < 4; ++r) {
        int row = row0 + wr * 64 + m * 16 + lg * 4 + r;
        out[(size_t)row * DM + col] = acc[m][n][r] + b;
      }
    }
}

extern "C" void kernel_launch(void* const* d_in, const int* in_sizes, int n_in,
                              void* d_out, int out_size, void* d_ws, size_t ws_size,
                              hipStream_t stream) {
  const float* x = (const float*)d_in[0];
  const float* Wq = (const float*)d_in[1];
  const float* bq = (const float*)d_in[2];
  const float* Wk = (const float*)d_in[3];
  const float* bk = (const float*)d_in[4];
  const float* Wv = (const float*)d_in[5];
  const float* bv = (const float*)d_in[6];
  const float* Wo = (const float*)d_in[7];
  const float* bo = (const float*)d_in[8];

  char* ws = (char*)d_ws;
  const size_t MB = 1024 * 1024;
  u16* xb = (u16*)(ws);             // 8 MB (x bf16; reused as attn out later)
  u16* Wqb = (u16*)(ws + 8 * MB);   // 2 MB
  u16* Wkb = (u16*)(ws + 10 * MB);  // 2 MB
  u16* Wvb = (u16*)(ws + 12 * MB);  // 2 MB
  u16* Wob = (u16*)(ws + 14 * MB);  // 2 MB
  u16* Qb = (u16*)(ws + 16 * MB);   // 8 MB
  u16* Kb = (u16*)(ws + 24 * MB);   // 8 MB
  u16* VT = (u16*)(ws + 32 * MB);   // 8 MB   (total 40 MB)
  u16* attnb = xb;                  // alias: xb dead after qkv_gemm

  cvt_kernel<<<4096, 256, 0, stream>>>(x, xb, MROWS * DM, 1.0f);
  // Wq carries 1/sqrt(Dh) * log2(e)
  cvt_kernel<<<1024, 256, 0, stream>>>(Wq, Wqb, DM * DM, 0.18033688011112042f);
  cvt_kernel<<<1024, 256, 0, stream>>>(Wk, Wkb, DM * DM, 1.0f);
  cvt_kernel<<<1024, 256, 0, stream>>>(Wv, Wvb, DM * DM, 1.0f);
  cvt_kernel<<<1024, 256, 0, stream>>>(Wo, Wob, DM * DM, 1.0f);

  qkv_gemm<<<dim3(24, 32), 256, 0, stream>>>(xb, Wqb, Wkb, Wvb, bq, bk, bv, Qb, Kb, VT);
  attn_kernel<<<dim3(16, 32), 256, 0, stream>>>(Qb, Kb, VT, attnb);
  out_gemm<<<dim3(8, 32), 256, 0, stream>>>(attnb, Wob, bo, (float*)d_out);
}